// Round 4
// baseline (167.361 us; speedup 1.0000x reference)
//
#include <hip/hip_runtime.h>

#define HH 128
#define WW 128
#define CIN 256
#define COUT 256
#define KTOT 2304   // 9 * 256, k = kk*256 + ci
#define HW (HH * WW)
#define NIT 36      // 9 taps * 4 channel-chunks of 64

typedef __attribute__((ext_vector_type(8))) short short8;
typedef __attribute__((ext_vector_type(4))) float f32x4;
typedef __attribute__((ext_vector_type(2))) float f32x2;

__device__ __forceinline__ unsigned rne_bf16(float f) {
  unsigned u = __float_as_uint(f);
  return (u + 0x7FFFu + ((u >> 16) & 1u)) >> 16;
}
__device__ __forceinline__ unsigned pack_bf16x2(float lo, float hi) {
  return rne_bf16(lo) | (rne_bf16(hi) << 16);
}
__device__ __forceinline__ unsigned cvt_pk_bf16(float lo, float hi) {
  unsigned r;
  asm("v_cvt_pk_bf16_f32 %0, %1, %2" : "=v"(r) : "v"(lo), "v"(hi));
  return r;
}
// unpack bf16x2 word -> {lo,hi} as exact f32 pair
__device__ __forceinline__ f32x2 up2(unsigned u) {
  f32x2 r;
  r.x = __uint_as_float(u << 16);
  r.y = __uint_as_float(u & 0xFFFF0000u);
  return r;
}
// packed dual-f32 mul/fma (weight pre-duplicated into both halves)
__device__ __forceinline__ f32x2 pkmul(f32x2 w, f32x2 v) {
  f32x2 d;
  asm("v_pk_mul_f32 %0, %1, %2" : "=v"(d) : "v"(w), "v"(v));
  return d;
}
__device__ __forceinline__ f32x2 pkfma(f32x2 w, f32x2 v, f32x2 c) {
  f32x2 d;
  asm("v_pk_fma_f32 %0, %1, %2, %3" : "=v"(d) : "v"(w), "v"(v), "v"(c));
  return d;
}

// Merged prep:
//  blocks [0,1024):    x [N][CIN][H][W] fp32 -> xt [N][H][W][CIN] bf16
//  blocks [1024,3328): weight [COUT][CIN][3][3] fp32 -> wB in MFMA-frag order:
//    element (co, k): k = it*64 + ksi*32 + l4*8 + e, lane = l4*16 + (co&15)
//    wB[(it*32 + (co>>4)*2 + ksi)*512 + lane*8 + e]
//  so a wave's B-frag load (j,ksi) is ONE fully-coalesced 1KB global load.
__global__ void prep_inputs(const float* __restrict__ x, const float* __restrict__ wsrc,
                            unsigned short* __restrict__ xt, unsigned short* __restrict__ wB) {
  int b = blockIdx.x;
  __shared__ float tile[64][129];
  if (b < 1024) {
    int cg = b & 3;
    int nh = b >> 2;
    int n = nh >> 7, h = nh & 127;
    int c0 = cg << 6;
    const float* xp = x + ((size_t)n * CIN * HH + h) * WW;
    for (int e = threadIdx.x; e < 64 * 128; e += 256) {
      int w = e & 127, ci = e >> 7;
      tile[ci][w] = xp[(size_t)(c0 + ci) * HW + w];
    }
    __syncthreads();
    unsigned* dst = (unsigned*)(xt + ((size_t)(n * HH + h) * WW) * CIN + c0);
    for (int e = threadIdx.x; e < 128 * 32; e += 256) {
      int w = e >> 5, cp = e & 31;
      dst[w * (CIN / 2) + cp] = pack_bf16x2(tile[2 * cp][w], tile[2 * cp + 1][w]);
    }
  } else {
    int o = (b - 1024) * 256 + threadIdx.x;
    if (o >= COUT * KTOT) return;
    int co = o / KTOT;
    int r = o - co * KTOT;      // r == k == kk*256 + ci
    int kk = r >> 8, ci = r & 255;
    int it = r >> 6;
    int rem = r & 63;
    int ksi = rem >> 5;
    int l4 = (rem >> 3) & 3;
    int e = rem & 7;
    int off = (it * 32 + (co >> 4) * 2 + ksi) * 512 + (l4 * 16 + (co & 15)) * 8 + e;
    wB[off] = rne_bf16(wsrc[(size_t)(co * CIN + ci) * 9 + kk]);
  }
}

// R8: R6 chassis (512 blocks x 512 thr, 8 waves, 32x64 wave tiles, 16 waves/CU)
// + B ENTIRELY OUT OF LDS: fragments loaded coalesced from frag-ordered wB
// straight into VGPRs (L1-resident 32KB/iter slice, L2-resident 1.2MB total).
// LDS holds only A (dbuf 16KB) -> one lgkmcnt-only barrier per iter; gather
// prefetches never drained by a barrier. LDS traffic 272 -> 80 KB/CU/iter.
__global__ __launch_bounds__(512, 4) void fused_deform_gemm(
    const float* __restrict__ obb, const unsigned short* __restrict__ xt,
    const unsigned short* __restrict__ wB, float* __restrict__ out,
    const int* __restrict__ stride_p) {
  int g = blockIdx.x;
  int xcd = g & 7, li = g >> 3;
  int u = xcd * 64 + li;   // 0..511; each XCD gets a contiguous 32-row band
  int mh = u & 1;          // which half of the image row
  int bm = u >> 1;         // row id 0..255
  int n = bm >> 7, h = bm & 127;
  int tid = threadIdx.x;

  // A only: 128B rows, phys byte = row*128 + (colbyte ^ ((row&7)<<4)); dbuf
  __shared__ __align__(16) unsigned short Alds[2][64 * 64];   // 16 KB

  float inv_s = 1.0f / (float)stride_p[0];

  int lane = tid & 63;
  int wv = tid >> 6;          // 0..7
  int wm = (wv & 1) * 32;     // wave pixel base (32px x 64co wave tile)
  int wn = (wv >> 1) * 64;    // wave cout base
  int l15 = lane & 15, l4 = lane >> 4;

  // A-build: 8 lanes per pixel, one 16B (8-channel) chunk per thread.
  int chunk8 = (lane & 7) * 8;
  int p = wv * 8 + (lane >> 3);    // this thread's pixel, 0..63
  int AldsOff = p * 128 + (((lane & 7) * 16) ^ ((p & 7) << 4));

  // per-thread obb params for pixel p
  float cx_, cy_, pa_, pb_, pc_, pd_;
  {
    int w = mh * 64 + p;
    const float* op = obb + ((size_t)n * 5 * HH + h) * WW + w;
    float xc = op[0] * inv_s;
    float yc = op[(size_t)1 * HW] * inv_s;
    float bw = op[(size_t)2 * HW] * inv_s;
    float bh = op[(size_t)3 * HW] * inv_s;
    float th = op[(size_t)4 * HW];
    float sn, cs;
    sincosf(th, &sn, &cs);
    float dw = bw * (1.0f / 3.0f), dh = bh * (1.0f / 3.0f);
    cx_ = xc; cy_ = yc;
    pa_ = dw * cs; pb_ = dh * sn;
    pc_ = dw * sn; pd_ = dh * cs;
  }

  f32x4 acc[2][4] = {};

  // B-frag base: cog = (wv>>1)*4 + j; byte = wB + (it*32 + cog*2 + ksi)*1024 + lane*16
  const char* wBb = (const char*)wB + ((wv >> 1) * 4) * 2048 + lane * 16;

  // A fragment-read column byte offsets (frag row &7 == l15&7)
  int rdXor = (l15 & 7) << 4;
  int rc0 = (l4 * 16) ^ rdXor;        // ks = 0
  int rc1 = (64 + l4 * 16) ^ rdXor;   // ks = 32

  f32x2 wgt2[4];  // bilinear weights (duplicated pairs)
  int boff[4];    // corner base element offsets
  uint4 pf[4];    // prefetched corner data
  uint4 aw;       // blended A chunk awaiting staging

  auto prep = [&](int kk) {
    float fky = (float)(kk / 3 - 1);
    float fkx = (float)(kk % 3 - 1);
    float sx = cx_ + fkx * pa_ - fky * pb_;
    float sy = cy_ + fkx * pc_ + fky * pd_;
    float fx = floorf(sx), fy = floorf(sy);
    float lx = sx - fx, ly = sy - fy;
    int x0 = (int)fx, y0 = (int)fy;
    float vy0 = (y0 >= 0 && y0 < HH) ? 1.0f : 0.0f;
    float vy1 = (y0 >= -1 && y0 < HH - 1) ? 1.0f : 0.0f;
    float vx0 = (x0 >= 0 && x0 < WW) ? 1.0f : 0.0f;
    float vx1 = (x0 >= -1 && x0 < WW - 1) ? 1.0f : 0.0f;
    float w00 = (1.0f - ly) * (1.0f - lx) * vy0 * vx0;
    float w01 = (1.0f - ly) * lx * vy0 * vx1;
    float w10 = ly * (1.0f - lx) * vy1 * vx0;
    float w11 = ly * lx * vy1 * vx1;
    wgt2[0] = (f32x2){w00, w00};
    wgt2[1] = (f32x2){w01, w01};
    wgt2[2] = (f32x2){w10, w10};
    wgt2[3] = (f32x2){w11, w11};
    int xc0 = min(max(x0, 0), WW - 1), xc1 = min(max(x0 + 1, 0), WW - 1);
    int yc0 = min(max(y0, 0), HH - 1), yc1 = min(max(y0 + 1, 0), HH - 1);
    int rb0 = (n * HH + yc0) * WW, rb1 = (n * HH + yc1) * WW;
    boff[0] = (rb0 + xc0) * CIN;
    boff[1] = (rb0 + xc1) * CIN;
    boff[2] = (rb1 + xc0) * CIN;
    boff[3] = (rb1 + xc1) * CIN;
  };

  auto issueA = [&](int cc) {
    int co = cc * 64 + chunk8;
#pragma unroll
    for (int c = 0; c < 4; ++c)
      pf[c] = *(const uint4*)(xt + boff[c] + co);
  };

  auto blendW = [&](unsigned a, unsigned b, unsigned c, unsigned d) -> unsigned {
    f32x2 s = pkmul(wgt2[0], up2(a));
    s = pkfma(wgt2[1], up2(b), s);
    s = pkfma(wgt2[2], up2(c), s);
    s = pkfma(wgt2[3], up2(d), s);
    return cvt_pk_bf16(s.x, s.y);
  };

  auto blendA = [&]() {
    uint4 r;
    r.x = blendW(pf[0].x, pf[1].x, pf[2].x, pf[3].x);
    r.y = blendW(pf[0].y, pf[1].y, pf[2].y, pf[3].y);
    r.z = blendW(pf[0].z, pf[1].z, pf[2].z, pf[3].z);
    r.w = blendW(pf[0].w, pf[1].w, pf[2].w, pf[3].w);
    aw = r;
  };

  char* AB = (char*)&Alds[0][0];

  // ---- prologue: stage tile 0 into buf0; gathers for tile 1 in flight ----
  prep(0);
  issueA(0);
  blendA();
  *(uint4*)(AB + AldsOff) = aw;
  issueA(1);
  asm volatile("s_waitcnt lgkmcnt(0)" ::: "memory");
  __builtin_amdgcn_s_barrier();
  asm volatile("" ::: "memory");

  for (int it = 0; it < NIT; ++it) {
    // ---- B fragments for THIS iter: 8 coalesced 1KB loads -> VGPRs ----
    const char* bp = wBb + it * 32768;
    short8 bf[8];
#pragma unroll
    for (int j = 0; j < 4; ++j) {
      bf[j * 2 + 0] = *(const short8*)(bp + j * 2048);
      bf[j * 2 + 1] = *(const short8*)(bp + j * 2048 + 1024);
    }

    // ---- blend tile it+1 into nbuf; issue gathers for tile it+2 ----
    if (it + 1 < NIT) {
      blendA();   // consumes pf (oldest vm-ops -> no overwait on bf)
      *(uint4*)(AB + ((it + 1) & 1) * 8192 + AldsOff) = aw;
      int t2 = it + 2;
      if (t2 < NIT) {
        if ((t2 & 3) == 0) prep(t2 >> 2);
        issueA(t2 & 3);   // newest vm-ops: stay in flight through MFMA + barrier
      }
    }

    // ---- MFMA on A[it&1] + bf ----
    char* ABr = AB + (it & 1) * 8192;
    __builtin_amdgcn_s_setprio(1);
#pragma unroll
    for (int ksi = 0; ksi < 2; ++ksi) {
      int rc = ksi ? rc1 : rc0;
      short8 af[2];
#pragma unroll
      for (int i = 0; i < 2; ++i)
        af[i] = *(const short8*)(ABr + (wm + i * 16 + l15) * 128 + rc);
#pragma unroll
      for (int j = 0; j < 4; ++j)
#pragma unroll
        for (int i = 0; i < 2; ++i)
          acc[i][j] = __builtin_amdgcn_mfma_f32_16x16x32_bf16(af[i], bf[j * 2 + ksi], acc[i][j], 0, 0, 0);
    }
    __builtin_amdgcn_s_setprio(0);

    // A-dbuf handoff: LDS ops only -> no vmcnt drain, gathers keep flying
    asm volatile("s_waitcnt lgkmcnt(0)" ::: "memory");
    __builtin_amdgcn_s_barrier();
    asm volatile("" ::: "memory");
  }

  // ---- epilogue: out[n][co][h][w], float4 along w ----
  float* outp = out + (size_t)n * COUT * HW + (size_t)h * WW + mh * 64;
#pragma unroll
  for (int i = 0; i < 2; ++i) {
    int w0 = wm + i * 16 + l4 * 4;
#pragma unroll
    for (int j = 0; j < 4; ++j) {
      int co = wn + j * 16 + l15;
      *(f32x4*)(outp + (size_t)co * HW + w0) = acc[i][j];
    }
  }
}

extern "C" void kernel_launch(void* const* d_in, const int* in_sizes, int n_in,
                              void* d_out, int out_size, void* d_ws, size_t ws_size,
                              hipStream_t stream) {
  const float* x = (const float*)d_in[0];
  const float* obb = (const float*)d_in[1];
  const float* wgt = (const float*)d_in[2];
  const int* stridep = (const int*)d_in[3];
  float* out = (float*)d_out;

  unsigned short* xt = (unsigned short*)d_ws;          // 2*128*128*256 bf16 = 16.8 MB
  unsigned short* wB = xt + (size_t)2 * HH * WW * CIN; // 256*2304 bf16 = 1.2 MB

  prep_inputs<<<dim3(1024 + 2304), 256, 0, stream>>>(x, wgt, xt, wB);
  fused_deform_gemm<<<dim3(512), 512, 0, stream>>>(obb, xt, wB, out, stridep);
}